// Round 1
// baseline (129.251 us; speedup 1.0000x reference)
//
#include <hip/hip_runtime.h>
#include <math.h>

#define NB 32
#define NT 4096
#define ND 1024

// ---------------------------------------------------------------------------
// Pass 1: one workgroup per (chunk, batch). 256 threads = 4 waves.
// Each wave owns rows_per_wave consecutive rows t. For each row:
//   - 64 lanes load the full D=1024 row as 4x float4 each (coalesced, 4 KB/row)
//   - dot with dhx fragment (held in registers), butterfly wave-reduce -> pax[t]
//   - online-softmax accumulate: acc += exp(pax-m) * eh_row, rescaling acc
//     only when the running max m increases (wave-uniform branch).
// Wave partials are merged in LDS to one (ctx[D], m) partial per workgroup.
// pax is written to the ax region of d_out (same size, overwritten in pass 2).
// ---------------------------------------------------------------------------
__global__ __launch_bounds__(256) void prodattn_pass1(
    const float* __restrict__ eh,
    const float* __restrict__ dhx,
    float* __restrict__ pax_out,   // [B, T]  (ax slot of d_out)
    float* __restrict__ ctx_out,   // [B, chunks, D]
    float* __restrict__ m_out,     // [B, chunks]
    int chunks, int rows_per_wave)
{
    const int chunk = blockIdx.x;
    const int b     = blockIdx.y;
    const int tid   = threadIdx.x;
    const int wave  = tid >> 6;
    const int lane  = tid & 63;

    // dhx fragment: lane holds d = (c*64+lane)*4 .. +3, c = 0..3
    const float4* dhx4 = reinterpret_cast<const float4*>(dhx + (size_t)b * ND);
    const float4 dv0 = dhx4[0 * 64 + lane];
    const float4 dv1 = dhx4[1 * 64 + lane];
    const float4 dv2 = dhx4[2 * 64 + lane];
    const float4 dv3 = dhx4[3 * 64 + lane];

    float4 a0 = make_float4(0.f, 0.f, 0.f, 0.f);
    float4 a1 = a0, a2 = a0, a3 = a0;
    float m = -INFINITY;

    const int row0 = chunk * (rows_per_wave * 4) + wave * rows_per_wave;
    const float4* ehb = reinterpret_cast<const float4*>(eh + (size_t)b * NT * ND);

    for (int i = 0; i < rows_per_wave; ++i) {
        const int t = row0 + i;
        const float4* er = ehb + (size_t)t * (ND / 4);
        const float4 e0 = er[0 * 64 + lane];
        const float4 e1 = er[1 * 64 + lane];
        const float4 e2 = er[2 * 64 + lane];
        const float4 e3 = er[3 * 64 + lane];

        float s =
            e0.x * dv0.x + e0.y * dv0.y + e0.z * dv0.z + e0.w * dv0.w +
            e1.x * dv1.x + e1.y * dv1.y + e1.z * dv1.z + e1.w * dv1.w +
            e2.x * dv2.x + e2.y * dv2.y + e2.z * dv2.z + e2.w * dv2.w +
            e3.x * dv3.x + e3.y * dv3.y + e3.z * dv3.z + e3.w * dv3.w;

        #pragma unroll
        for (int off = 32; off > 0; off >>= 1)
            s += __shfl_xor(s, off, 64);
        // all 64 lanes now hold the same pax value

        if (lane == 0) pax_out[(size_t)b * NT + t] = s;

        float w;
        if (s > m) {                    // wave-uniform branch
            const float scale = __expf(m - s);   // exp(-inf)=0 on first row
            a0.x *= scale; a0.y *= scale; a0.z *= scale; a0.w *= scale;
            a1.x *= scale; a1.y *= scale; a1.z *= scale; a1.w *= scale;
            a2.x *= scale; a2.y *= scale; a2.z *= scale; a2.w *= scale;
            a3.x *= scale; a3.y *= scale; a3.z *= scale; a3.w *= scale;
            m = s;
            w = 1.0f;
        } else {
            w = __expf(s - m);
        }
        a0.x += w * e0.x; a0.y += w * e0.y; a0.z += w * e0.z; a0.w += w * e0.w;
        a1.x += w * e1.x; a1.y += w * e1.y; a1.z += w * e1.z; a1.w += w * e1.w;
        a2.x += w * e2.x; a2.y += w * e2.y; a2.z += w * e2.z; a2.w += w * e2.w;
        a3.x += w * e3.x; a3.y += w * e3.y; a3.z += w * e3.z; a3.w += w * e3.w;
    }

    // ---- merge the 4 wave partials into one workgroup partial ----
    __shared__ float  s_m[4];
    __shared__ float4 s_acc[4][ND / 4];   // 16 KiB

    if (lane == 0) s_m[wave] = m;
    __syncthreads();
    const float M = fmaxf(fmaxf(s_m[0], s_m[1]), fmaxf(s_m[2], s_m[3]));
    const float f = __expf(m - M);

    a0.x *= f; a0.y *= f; a0.z *= f; a0.w *= f;
    a1.x *= f; a1.y *= f; a1.z *= f; a1.w *= f;
    a2.x *= f; a2.y *= f; a2.z *= f; a2.w *= f;
    a3.x *= f; a3.y *= f; a3.z *= f; a3.w *= f;
    s_acc[wave][0 * 64 + lane] = a0;
    s_acc[wave][1 * 64 + lane] = a1;
    s_acc[wave][2 * 64 + lane] = a2;
    s_acc[wave][3 * 64 + lane] = a3;
    __syncthreads();

    float4 r = s_acc[0][tid];
    const float4 r1 = s_acc[1][tid];
    const float4 r2 = s_acc[2][tid];
    const float4 r3 = s_acc[3][tid];
    r.x += r1.x + r2.x + r3.x;
    r.y += r1.y + r2.y + r3.y;
    r.z += r1.z + r2.z + r3.z;
    r.w += r1.w + r2.w + r3.w;

    reinterpret_cast<float4*>(ctx_out + ((size_t)b * chunks + chunk) * ND)[tid] = r;
    if (tid == 0) m_out[b * chunks + chunk] = M;
}

// ---------------------------------------------------------------------------
// Pass 2: one workgroup per batch. Computes global M, L from stored pax,
// rewrites pax -> ax in place, and merges chunk contexts into sx.
// ---------------------------------------------------------------------------
__global__ __launch_bounds__(256) void prodattn_pass2(
    float* __restrict__ sx_out,          // [B, D]  (d_out offset 0)
    float* __restrict__ ax_inout,        // [B, T]  (pax on entry, ax on exit)
    const float* __restrict__ ctx,       // [B, chunks, D]
    const float* __restrict__ m_arr,     // [B, chunks]
    int chunks)
{
    const int b    = blockIdx.x;
    const int tid  = threadIdx.x;
    const int wave = tid >> 6;
    const int lane = tid & 63;

    __shared__ float red[4];
    float* pax = ax_inout + (size_t)b * NT;

    // global max over T
    float lm = -INFINITY;
    for (int i = tid; i < NT; i += 256) lm = fmaxf(lm, pax[i]);
    #pragma unroll
    for (int off = 32; off > 0; off >>= 1)
        lm = fmaxf(lm, __shfl_xor(lm, off, 64));
    if (lane == 0) red[wave] = lm;
    __syncthreads();
    const float M = fmaxf(fmaxf(red[0], red[1]), fmaxf(red[2], red[3]));
    __syncthreads();

    // global sum of exp
    float ls = 0.f;
    for (int i = tid; i < NT; i += 256) ls += __expf(pax[i] - M);
    #pragma unroll
    for (int off = 32; off > 0; off >>= 1)
        ls += __shfl_xor(ls, off, 64);
    if (lane == 0) red[wave] = ls;
    __syncthreads();
    const float L   = red[0] + red[1] + red[2] + red[3];
    const float inv = 1.0f / L;

    // ax in place (each index touched by exactly one thread, read-then-write)
    for (int i = tid; i < NT; i += 256)
        pax[i] = __expf(pax[i] - M) * inv;

    // sx: merge chunk contexts (thread tid owns float4 index tid of D)
    float4 s = make_float4(0.f, 0.f, 0.f, 0.f);
    for (int c = 0; c < chunks; ++c) {
        const float w = __expf(m_arr[b * chunks + c] - M);
        const float4 v =
            reinterpret_cast<const float4*>(ctx + ((size_t)b * chunks + c) * ND)[tid];
        s.x += w * v.x; s.y += w * v.y; s.z += w * v.z; s.w += w * v.w;
    }
    s.x *= inv; s.y *= inv; s.z *= inv; s.w *= inv;
    reinterpret_cast<float4*>(sx_out + (size_t)b * ND)[tid] = s;
}

extern "C" void kernel_launch(void* const* d_in, const int* in_sizes, int n_in,
                              void* d_out, int out_size, void* d_ws, size_t ws_size,
                              hipStream_t stream) {
    const float* eh  = (const float*)d_in[0];   // [B, T, D] fp32
    const float* dhx = (const float*)d_in[1];   // [B, 1, D] fp32

    float* out = (float*)d_out;
    float* sx  = out;                // [B, D]   = 32768 floats
    float* ax  = out + NB * ND;      // [B, T]   = 131072 floats (pax staging)

    // pick chunk count that fits the workspace: ctx [B*chunks*D] + m [B*chunks]
    int chunks = 32;
    while (chunks > 1 &&
           (size_t)NB * chunks * (ND + 1) * sizeof(float) > ws_size)
        chunks >>= 1;

    float* ctx   = (float*)d_ws;                       // [B, chunks, D]
    float* m_arr = ctx + (size_t)NB * chunks * ND;     // [B, chunks]

    const int rows_per_wave = NT / (chunks * 4);

    dim3 grid1(chunks, NB);
    prodattn_pass1<<<grid1, 256, 0, stream>>>(eh, dhx, ax, ctx, m_arr,
                                              chunks, rows_per_wave);
    prodattn_pass2<<<NB, 256, 0, stream>>>(sx, ax, ctx, m_arr, chunks);
}

// Round 2
// 113.568 us; speedup vs baseline: 1.1381x; 1.1381x over previous
//
#include <hip/hip_runtime.h>
#include <math.h>

#define NB 32
#define NT 4096
#define ND 1024
#define SPANS 4   // ax-rewrite workgroups per batch in pass 2

// ---------------------------------------------------------------------------
// Pass 1: one workgroup per (chunk, batch), 256 threads = 4 waves.
// Each wave owns rows_per_wave consecutive rows. Software-pipelined: two
// register buffers (A, B) of 2 rows (8 KB) each; stage s+1's loads are issued
// before stage s's compute, so every wave keeps ~8 KB outstanding while the
// shuffle-reduce chain runs. Online softmax is branchless:
//   mn = max(m, s0, s1); acc = acc*exp(m-mn) + w0*e + w1*f; l = l*exp(m-mn)+w0+w1
// Per-chunk (ctx[D], M, L) partials go to workspace; raw pax goes to the ax
// slot of d_out (rewritten in pass 2).
// ---------------------------------------------------------------------------

#define LOAD2(P, S_) do {                                                     \
    const float4* er0_ = ehb + (size_t)(row0 + 2*(S_)) * (ND/4);              \
    const float4* er1_ = er0_ + (ND/4);                                       \
    P##_e0 = er0_[0*64+lane]; P##_e1 = er0_[1*64+lane];                       \
    P##_e2 = er0_[2*64+lane]; P##_e3 = er0_[3*64+lane];                       \
    P##_f0 = er1_[0*64+lane]; P##_f1 = er1_[1*64+lane];                       \
    P##_f2 = er1_[2*64+lane]; P##_f3 = er1_[3*64+lane];                       \
} while (0)

#define COMPUTE2(P, S_) do {                                                  \
    float s0_ =                                                               \
        P##_e0.x*dv0.x + P##_e0.y*dv0.y + P##_e0.z*dv0.z + P##_e0.w*dv0.w +   \
        P##_e1.x*dv1.x + P##_e1.y*dv1.y + P##_e1.z*dv1.z + P##_e1.w*dv1.w +   \
        P##_e2.x*dv2.x + P##_e2.y*dv2.y + P##_e2.z*dv2.z + P##_e2.w*dv2.w +   \
        P##_e3.x*dv3.x + P##_e3.y*dv3.y + P##_e3.z*dv3.z + P##_e3.w*dv3.w;    \
    float s1_ =                                                               \
        P##_f0.x*dv0.x + P##_f0.y*dv0.y + P##_f0.z*dv0.z + P##_f0.w*dv0.w +   \
        P##_f1.x*dv1.x + P##_f1.y*dv1.y + P##_f1.z*dv1.z + P##_f1.w*dv1.w +   \
        P##_f2.x*dv2.x + P##_f2.y*dv2.y + P##_f2.z*dv2.z + P##_f2.w*dv2.w +   \
        P##_f3.x*dv3.x + P##_f3.y*dv3.y + P##_f3.z*dv3.z + P##_f3.w*dv3.w;    \
    _Pragma("unroll")                                                         \
    for (int off_ = 32; off_ > 0; off_ >>= 1) {                               \
        s0_ += __shfl_xor(s0_, off_, 64);                                     \
        s1_ += __shfl_xor(s1_, off_, 64);                                     \
    }                                                                         \
    if (lane == 0) {                                                          \
        paxb[row0 + 2*(S_)]     = s0_;                                        \
        paxb[row0 + 2*(S_) + 1] = s1_;                                        \
    }                                                                         \
    const float mn_ = fmaxf(m, fmaxf(s0_, s1_));                              \
    const float sc_ = __expf(m  - mn_);                                       \
    const float w0_ = __expf(s0_ - mn_);                                      \
    const float w1_ = __expf(s1_ - mn_);                                      \
    m = mn_;                                                                  \
    l = l*sc_ + w0_ + w1_;                                                    \
    a0.x = a0.x*sc_ + w0_*P##_e0.x + w1_*P##_f0.x;                            \
    a0.y = a0.y*sc_ + w0_*P##_e0.y + w1_*P##_f0.y;                            \
    a0.z = a0.z*sc_ + w0_*P##_e0.z + w1_*P##_f0.z;                            \
    a0.w = a0.w*sc_ + w0_*P##_e0.w + w1_*P##_f0.w;                            \
    a1.x = a1.x*sc_ + w0_*P##_e1.x + w1_*P##_f1.x;                            \
    a1.y = a1.y*sc_ + w0_*P##_e1.y + w1_*P##_f1.y;                            \
    a1.z = a1.z*sc_ + w0_*P##_e1.z + w1_*P##_f1.z;                            \
    a1.w = a1.w*sc_ + w0_*P##_e1.w + w1_*P##_f1.w;                            \
    a2.x = a2.x*sc_ + w0_*P##_e2.x + w1_*P##_f2.x;                            \
    a2.y = a2.y*sc_ + w0_*P##_e2.y + w1_*P##_f2.y;                            \
    a2.z = a2.z*sc_ + w0_*P##_e2.z + w1_*P##_f2.z;                            \
    a2.w = a2.w*sc_ + w0_*P##_e2.w + w1_*P##_f2.w;                            \
    a3.x = a3.x*sc_ + w0_*P##_e3.x + w1_*P##_f3.x;                            \
    a3.y = a3.y*sc_ + w0_*P##_e3.y + w1_*P##_f3.y;                            \
    a3.z = a3.z*sc_ + w0_*P##_e3.z + w1_*P##_f3.z;                            \
    a3.w = a3.w*sc_ + w0_*P##_e3.w + w1_*P##_f3.w;                            \
} while (0)

__global__ __launch_bounds__(256) void prodattn_pass1(
    const float* __restrict__ eh,
    const float* __restrict__ dhx,
    float* __restrict__ pax_out,   // [B, T]
    float* __restrict__ ctx_out,   // [B, chunks, D]
    float* __restrict__ m_out,     // [B, chunks]
    float* __restrict__ l_out,     // [B, chunks]
    int chunks, int rows_per_wave)
{
    const int chunk = blockIdx.x;
    const int b     = blockIdx.y;
    const int tid   = threadIdx.x;
    const int wave  = tid >> 6;
    const int lane  = tid & 63;

    const float4* dhx4 = reinterpret_cast<const float4*>(dhx + (size_t)b * ND);
    const float4 dv0 = dhx4[0*64 + lane];
    const float4 dv1 = dhx4[1*64 + lane];
    const float4 dv2 = dhx4[2*64 + lane];
    const float4 dv3 = dhx4[3*64 + lane];

    float4 a0 = make_float4(0.f,0.f,0.f,0.f), a1 = a0, a2 = a0, a3 = a0;
    float m = -INFINITY, l = 0.f;

    const int row0 = chunk * (rows_per_wave * 4) + wave * rows_per_wave;
    const float4* ehb = reinterpret_cast<const float4*>(eh + (size_t)b * NT * ND);
    float* paxb = pax_out + (size_t)b * NT;

    float4 A_e0, A_e1, A_e2, A_e3, A_f0, A_f1, A_f2, A_f3;
    float4 B_e0, B_e1, B_e2, B_e3, B_f0, B_f1, B_f2, B_f3;

    const int S = rows_per_wave >> 1;   // stages of 2 rows; S is even (>=2)

    LOAD2(A, 0);
    int s = 0;
    for (; s + 2 < S; s += 2) {
        LOAD2(B, s + 1);
        COMPUTE2(A, s);
        LOAD2(A, s + 2);
        COMPUTE2(B, s + 1);
    }
    LOAD2(B, S - 1);
    COMPUTE2(A, S - 2);
    COMPUTE2(B, S - 1);

    // ---- merge 4 wave partials -> one workgroup partial ----
    __shared__ float  s_m[4];
    __shared__ float  s_l[4];
    __shared__ float4 s_acc[4][ND / 4];   // 16 KiB

    if (lane == 0) s_m[wave] = m;
    __syncthreads();
    const float M = fmaxf(fmaxf(s_m[0], s_m[1]), fmaxf(s_m[2], s_m[3]));
    const float f = __expf(m - M);
    if (lane == 0) s_l[wave] = l * f;

    a0.x *= f; a0.y *= f; a0.z *= f; a0.w *= f;
    a1.x *= f; a1.y *= f; a1.z *= f; a1.w *= f;
    a2.x *= f; a2.y *= f; a2.z *= f; a2.w *= f;
    a3.x *= f; a3.y *= f; a3.z *= f; a3.w *= f;
    s_acc[wave][0*64 + lane] = a0;
    s_acc[wave][1*64 + lane] = a1;
    s_acc[wave][2*64 + lane] = a2;
    s_acc[wave][3*64 + lane] = a3;
    __syncthreads();

    float4 r = s_acc[0][tid];
    const float4 r1 = s_acc[1][tid];
    const float4 r2 = s_acc[2][tid];
    const float4 r3 = s_acc[3][tid];
    r.x += r1.x + r2.x + r3.x;
    r.y += r1.y + r2.y + r3.y;
    r.z += r1.z + r2.z + r3.z;
    r.w += r1.w + r2.w + r3.w;

    reinterpret_cast<float4*>(ctx_out + ((size_t)b * chunks + chunk) * ND)[tid] = r;
    if (tid == 0) {
        m_out[b * chunks + chunk] = M;
        l_out[b * chunks + chunk] = s_l[0] + s_l[1] + s_l[2] + s_l[3];
    }
}

// ---------------------------------------------------------------------------
// Pass 2: grid (NB, SPANS+1). Every WG derives (M, 1/L) from the per-chunk
// (m, l) arrays (64 tiny loads, wave-0 butterfly). Roles 0..SPANS-1 rewrite
// one ax span (exp(pax-M)/L); role SPANS merges the chunk contexts into sx
// with 4 independent accumulators so the L2/L3 loads pipeline.
// ---------------------------------------------------------------------------
__global__ __launch_bounds__(256) void prodattn_pass2(
    float* __restrict__ sx_out,          // [B, D]
    float* __restrict__ ax_inout,        // [B, T] (pax in, ax out)
    const float* __restrict__ ctx,       // [B, chunks, D]
    const float* __restrict__ m_arr,     // [B, chunks]
    const float* __restrict__ l_arr,     // [B, chunks]
    int chunks)
{
    const int b    = blockIdx.x;
    const int role = blockIdx.y;
    const int tid  = threadIdx.x;
    const int wave = tid >> 6;
    const int lane = tid & 63;

    __shared__ float sM, sInv;
    if (wave == 0) {
        float mv = (lane < chunks) ? m_arr[b * chunks + lane] : -INFINITY;
        float lv = (lane < chunks) ? l_arr[b * chunks + lane] : 0.f;
        float M = mv;
        #pragma unroll
        for (int off = 32; off > 0; off >>= 1)
            M = fmaxf(M, __shfl_xor(M, off, 64));
        float c = lv * __expf(mv - M);
        #pragma unroll
        for (int off = 32; off > 0; off >>= 1)
            c += __shfl_xor(c, off, 64);
        if (lane == 0) { sM = M; sInv = 1.0f / c; }
    }
    __syncthreads();
    const float M   = sM;
    const float inv = sInv;

    if (role < SPANS) {
        // rewrite NT/SPANS = 1024 pax values -> ax (one float4 per thread)
        float4* ax4 = reinterpret_cast<float4*>(ax_inout + (size_t)b * NT)
                      + role * (NT / 4 / SPANS);
        float4 v = ax4[tid];
        v.x = __expf(v.x - M) * inv;
        v.y = __expf(v.y - M) * inv;
        v.z = __expf(v.z - M) * inv;
        v.w = __expf(v.w - M) * inv;
        ax4[tid] = v;
    } else {
        // merge chunk contexts -> sx
        const float4* cb = reinterpret_cast<const float4*>(ctx + (size_t)b * chunks * ND);
        const float*  mb = m_arr + b * chunks;
        float4 acc0 = make_float4(0.f,0.f,0.f,0.f), acc1 = acc0, acc2 = acc0, acc3 = acc0;
        int c = 0;
        for (; c + 3 < chunks; c += 4) {
            const float w0 = __expf(mb[c+0] - M);
            const float w1 = __expf(mb[c+1] - M);
            const float w2 = __expf(mb[c+2] - M);
            const float w3 = __expf(mb[c+3] - M);
            const float4 v0 = cb[(size_t)(c+0)*(ND/4) + tid];
            const float4 v1 = cb[(size_t)(c+1)*(ND/4) + tid];
            const float4 v2 = cb[(size_t)(c+2)*(ND/4) + tid];
            const float4 v3 = cb[(size_t)(c+3)*(ND/4) + tid];
            acc0.x += w0*v0.x; acc0.y += w0*v0.y; acc0.z += w0*v0.z; acc0.w += w0*v0.w;
            acc1.x += w1*v1.x; acc1.y += w1*v1.y; acc1.z += w1*v1.z; acc1.w += w1*v1.w;
            acc2.x += w2*v2.x; acc2.y += w2*v2.y; acc2.z += w2*v2.z; acc2.w += w2*v2.w;
            acc3.x += w3*v3.x; acc3.y += w3*v3.y; acc3.z += w3*v3.z; acc3.w += w3*v3.w;
        }
        for (; c < chunks; ++c) {
            const float w = __expf(mb[c] - M);
            const float4 v = cb[(size_t)c*(ND/4) + tid];
            acc0.x += w*v.x; acc0.y += w*v.y; acc0.z += w*v.z; acc0.w += w*v.w;
        }
        float4 r;
        r.x = (acc0.x + acc1.x + acc2.x + acc3.x) * inv;
        r.y = (acc0.y + acc1.y + acc2.y + acc3.y) * inv;
        r.z = (acc0.z + acc1.z + acc2.z + acc3.z) * inv;
        r.w = (acc0.w + acc1.w + acc2.w + acc3.w) * inv;
        reinterpret_cast<float4*>(sx_out + (size_t)b * ND)[tid] = r;
    }
}

extern "C" void kernel_launch(void* const* d_in, const int* in_sizes, int n_in,
                              void* d_out, int out_size, void* d_ws, size_t ws_size,
                              hipStream_t stream) {
    const float* eh  = (const float*)d_in[0];   // [B, T, D] fp32
    const float* dhx = (const float*)d_in[1];   // [B, 1, D] fp32

    float* out = (float*)d_out;
    float* sx  = out;                // [B, D]
    float* ax  = out + NB * ND;      // [B, T] (pax staging, then ax)

    // workspace: ctx [B*chunks*D] + m [B*chunks] + l [B*chunks]
    int chunks = 32;
    while (chunks > 1 &&
           (size_t)NB * chunks * (ND + 2) * sizeof(float) > ws_size)
        chunks >>= 1;

    float* ctx   = (float*)d_ws;                       // [B, chunks, D]
    float* m_arr = ctx + (size_t)NB * chunks * ND;     // [B, chunks]
    float* l_arr = m_arr + (size_t)NB * chunks;        // [B, chunks]

    const int rows_per_wave = NT / (chunks * 4);

    dim3 grid1(chunks, NB);
    prodattn_pass1<<<grid1, 256, 0, stream>>>(eh, dhx, ax, ctx, m_arr, l_arr,
                                              chunks, rows_per_wave);
    dim3 grid2(NB, SPANS + 1);
    prodattn_pass2<<<grid2, 256, 0, stream>>>(sx, ax, ctx, m_arr, l_arr, chunks);
}